// Round 1
// baseline (32.699 us; speedup 1.0000x reference)
//
#include <hip/hip_runtime.h>

#define BB   256
#define NN   128
#define AA   15
#define HH   32
#define MIDD 256

__global__ __launch_bounds__(256) void gacq_fused(
    const float* __restrict__ obs,
    const float* __restrict__ mw1, const float* __restrict__ mb1,
    const float* __restrict__ mw2, const float* __restrict__ mb2,
    const float* __restrict__ aw1, const float* __restrict__ ab1,
    const float* __restrict__ aw2, const float* __restrict__ ab2,
    const float* __restrict__ cw1, const float* __restrict__ cb1,
    const float* __restrict__ cw2, const float* __restrict__ cb2,
    const float* __restrict__ cw3, const float* __restrict__ cb3,
    const float* __restrict__ cw4, const float* __restrict__ cb4,
    float* __restrict__ out)
{
    __shared__ __align__(16) float obs_s[NN];
    __shared__ __align__(16) float v_s[NN][HH];   // 16 KB
    __shared__ float part_s[2][NN];
    __shared__ float msg_s[NN];
    __shared__ float red_s[4][16];
    __shared__ __align__(16) float h1_s[MIDD];
    __shared__ __align__(16) float h2_s[MIDD];

    const int b    = blockIdx.x;
    const int t    = threadIdx.x;
    const int lane = t & 63;
    const int wave = t >> 6;

    // ---- load obs row ----
    if (t < NN) obs_s[t] = obs[b * NN + t];
    __syncthreads();

    // ---- precompute v[j][k] = obs[j]*mw1[2][k] + coor_j*mw1[3][k] + mb1[k] ----
    for (int e = t; e < NN * HH; e += 256) {
        const int j = e >> 5, k = e & 31;
        const float coor = (float)j * (1.0f / (float)NN);
        v_s[j][k] = obs_s[j] * mw1[2 * HH + k] + coor * mw1[3 * HH + k] + mb1[k];
    }

    // per-thread identity: output row i, j-half (later reused as k-half)
    const int   i      = t & 127;
    const int   half   = t >> 7;
    const float coor_i = (float)i * (1.0f / (float)NN);
    const float obs_i  = obs_s[i];   // obs_s stable since first sync

    // u[i][k] = obs_i*mw1[0][k] + coor_i*mw1[1][k]  (registers; weights via s_load)
    float u[HH], w2[HH];
#pragma unroll
    for (int k = 0; k < HH; ++k) {
        u[k]  = obs_i * mw1[k] + coor_i * mw1[HH + k];
        w2[k] = mw2[k];
    }
    __syncthreads();   // v_s ready

    // ---- stage 1: msg[b,i] = sum_j sum_k relu(u[i][k]+v[j][k]) * w2[k] ----
    float acc0 = 0.f, acc1 = 0.f, acc2 = 0.f, acc3 = 0.f;
    const int j0 = half * 64;
#pragma unroll 2
    for (int j = j0; j < j0 + 64; ++j) {
        const float4* vrow = (const float4*)(&v_s[j][0]);   // wave-uniform -> broadcast
#pragma unroll
        for (int g = 0; g < 8; ++g) {
            const float4 v4 = vrow[g];
            acc0 += fmaxf(u[4 * g + 0] + v4.x, 0.f) * w2[4 * g + 0];
            acc1 += fmaxf(u[4 * g + 1] + v4.y, 0.f) * w2[4 * g + 1];
            acc2 += fmaxf(u[4 * g + 2] + v4.z, 0.f) * w2[4 * g + 2];
            acc3 += fmaxf(u[4 * g + 3] + v4.w, 0.f) * w2[4 * g + 3];
        }
    }
    part_s[half][i] = (acc0 + acc1) + (acc2 + acc3);
    __syncthreads();
    if (t < NN) msg_s[t] = part_s[0][t] + part_s[1][t] + (float)NN * mb2[0];
    __syncthreads();

    // ---- stage 2: actor logits[b,a] = sum_i sum_k relu(p[i][k]+q[a][k]) * aw2[k] ----
    // p[i][k] = msg_i*aw1[0][k] + coor_i*aw1[1][k] + ab1[k]; q[a][k] = a*aw1[2][k]
    // thread handles row i and k-half `half` (16 k's)
    {
        const float msg_i = msg_s[i];
        float p[16];
#pragma unroll
        for (int kk = 0; kk < 16; ++kk) {
            const int k = half * 16 + kk;
            p[kk] = msg_i * aw1[k] + coor_i * aw1[HH + k] + ab1[k];
        }
        float lacc[AA];
#pragma unroll
        for (int a = 0; a < AA; ++a) lacc[a] = 0.f;
#pragma unroll
        for (int a = 0; a < AA; ++a) {
            const float fa = (float)a;
#pragma unroll
            for (int kk = 0; kk < 16; ++kk) {
                const int k = half * 16 + kk;
                lacc[a] += fmaxf(p[kk] + fa * aw1[2 * HH + k], 0.f) * aw2[k];
            }
        }
#pragma unroll
        for (int a = 0; a < AA; ++a) {
            float s = lacc[a];
#pragma unroll
            for (int off = 32; off > 0; off >>= 1) s += __shfl_xor(s, off);
            if (lane == 0) red_s[wave][a] = s;
        }
    }
    __syncthreads();
    if (t < AA)
        out[b * AA + t] = red_s[0][t] + red_s[1][t] + red_s[2][t] + red_s[3][t]
                          + (float)NN * ab2[0];

    // ---- stage 3: critic MLP (thread t = hidden unit m) ----
    {   // layer 1: 128 -> 256
        float a0 = 0.f, a1 = 0.f, a2 = 0.f, a3 = 0.f;
#pragma unroll 4
        for (int n = 0; n < NN; n += 4) {
            const float4 o4 = *(const float4*)&obs_s[n];
            a0 += o4.x * cw1[(n + 0) * MIDD + t];
            a1 += o4.y * cw1[(n + 1) * MIDD + t];
            a2 += o4.z * cw1[(n + 2) * MIDD + t];
            a3 += o4.w * cw1[(n + 3) * MIDD + t];
        }
        h1_s[t] = fmaxf(cb1[t] + ((a0 + a1) + (a2 + a3)), 0.f);
    }
    __syncthreads();
    {   // layer 2: 256 -> 256
        float a0 = 0.f, a1 = 0.f, a2 = 0.f, a3 = 0.f;
#pragma unroll 4
        for (int k = 0; k < MIDD; k += 4) {
            const float4 h4 = *(const float4*)&h1_s[k];
            a0 += h4.x * cw2[(k + 0) * MIDD + t];
            a1 += h4.y * cw2[(k + 1) * MIDD + t];
            a2 += h4.z * cw2[(k + 2) * MIDD + t];
            a3 += h4.w * cw2[(k + 3) * MIDD + t];
        }
        h2_s[t] = fmaxf(cb2[t] + ((a0 + a1) + (a2 + a3)), 0.f);
    }
    __syncthreads();
    {   // layer 3: 256 -> 256, then head 256 -> 1
        float a0 = 0.f, a1 = 0.f, a2 = 0.f, a3 = 0.f;
#pragma unroll 4
        for (int k = 0; k < MIDD; k += 4) {
            const float4 h4 = *(const float4*)&h2_s[k];
            a0 += h4.x * cw3[(k + 0) * MIDD + t];
            a1 += h4.y * cw3[(k + 1) * MIDD + t];
            a2 += h4.z * cw3[(k + 2) * MIDD + t];
            a3 += h4.w * cw3[(k + 3) * MIDD + t];
        }
        const float h3 = fmaxf(cb3[t] + ((a0 + a1) + (a2 + a3)), 0.f);
        float pv = h3 * cw4[t];
#pragma unroll
        for (int off = 32; off > 0; off >>= 1) pv += __shfl_xor(pv, off);
        __syncthreads();
        if (lane == 0) red_s[wave][0] = pv;
        __syncthreads();
        if (t == 0)
            out[BB * AA + b] = red_s[0][0] + red_s[1][0] + red_s[2][0] + red_s[3][0]
                               + cb4[0];
    }
}

extern "C" void kernel_launch(void* const* d_in, const int* in_sizes, int n_in,
                              void* d_out, int out_size, void* d_ws, size_t ws_size,
                              hipStream_t stream) {
    const float* obs = (const float*)d_in[0];
    const float* mw1 = (const float*)d_in[1];
    const float* mb1 = (const float*)d_in[2];
    const float* mw2 = (const float*)d_in[3];
    const float* mb2 = (const float*)d_in[4];
    const float* aw1 = (const float*)d_in[5];
    const float* ab1 = (const float*)d_in[6];
    const float* aw2 = (const float*)d_in[7];
    const float* ab2 = (const float*)d_in[8];
    const float* cw1 = (const float*)d_in[9];
    const float* cb1 = (const float*)d_in[10];
    const float* cw2 = (const float*)d_in[11];
    const float* cb2 = (const float*)d_in[12];
    const float* cw3 = (const float*)d_in[13];
    const float* cb3 = (const float*)d_in[14];
    const float* cw4 = (const float*)d_in[15];
    const float* cb4 = (const float*)d_in[16];
    float* out = (float*)d_out;

    gacq_fused<<<dim3(BB), dim3(256), 0, stream>>>(
        obs, mw1, mb1, mw2, mb2, aw1, ab1, aw2, ab2,
        cw1, cb1, cw2, cb2, cw3, cb3, cw4, cb4, out);
}

// Round 2
// 28.820 us; speedup vs baseline: 1.1346x; 1.1346x over previous
//
#include <hip/hip_runtime.h>

#define BB   256
#define NN   128
#define AA   15
#define HH   32
#define MIDD 256

// ---------------- kernel 1: messenger+actor partials (blocks 0..1023)
//                  + critic (blocks 1024..1279) ----------------
__global__ __launch_bounds__(256, 4) void gacq_main(
    const float* __restrict__ obs,
    const float* __restrict__ mw1, const float* __restrict__ mb1,
    const float* __restrict__ mw2, const float* __restrict__ mb2,
    const float* __restrict__ aw1, const float* __restrict__ ab1,
    const float* __restrict__ aw2, const float* __restrict__ ab2,
    const float* __restrict__ cw1, const float* __restrict__ cb1,
    const float* __restrict__ cw2, const float* __restrict__ cb2,
    const float* __restrict__ cw3, const float* __restrict__ cb3,
    const float* __restrict__ cw4, const float* __restrict__ cb4,
    float* __restrict__ out, float* __restrict__ ws)
{
    __shared__ __align__(16) float obs_s[NN];
    __shared__ __align__(16) float v_s[NN][HH];     // 16 KB
    __shared__ float part_s[8][32];
    __shared__ float msg_s[32];
    __shared__ float red_s[4][16];
    __shared__ __align__(16) float h1_s[MIDD];
    __shared__ __align__(16) float h2_s[MIDD];

    const int blk  = blockIdx.x;
    const int t    = threadIdx.x;
    const int lane = t & 63;
    const int wave = t >> 6;

    if (blk < 4 * BB) {
        // ================= messenger + actor-partial block =================
        const int b = blk >> 2;
        const int h = blk & 3;          // row-quarter: rows [32h, 32h+32)

        if (t < NN) obs_s[t] = obs[b * NN + t];
        __syncthreads();

        // v[j][k] = obs[j]*mw1[2][k] + coor_j*mw1[3][k] + mb1[k], all 128 j
        for (int e = t; e < NN * HH; e += 256) {
            const int j = e >> 5, k = e & 31;
            v_s[j][k] = obs_s[j] * mw1[2 * HH + k]
                      + ((float)j * (1.0f / (float)NN)) * mw1[3 * HH + k]
                      + mb1[k];
        }

        const int   r      = t & 31;          // local row
        const int   i      = h * 32 + r;      // global row
        const int   jg     = t >> 5;          // 0..7, 16 j each
        const float coor_i = (float)i * (1.0f / (float)NN);
        const float obs_i  = obs_s[i];

        float u[HH], w2[HH];
#pragma unroll
        for (int k = 0; k < HH; ++k) {
            u[k]  = obs_i * mw1[k] + coor_i * mw1[HH + k];
            w2[k] = mw2[k];
        }
        __syncthreads();   // v_s ready

        // ---- stage 1: partial over 16 j ----
        float acc0 = 0.f, acc1 = 0.f, acc2 = 0.f, acc3 = 0.f;
        const int j0 = jg * 16;
#pragma unroll 2
        for (int j = j0; j < j0 + 16; ++j) {
            const float4* vrow = (const float4*)(&v_s[j][0]); // 2 uniq addr/wave
#pragma unroll
            for (int g = 0; g < 8; ++g) {
                const float4 v4 = vrow[g];
                acc0 += fmaxf(u[4 * g + 0] + v4.x, 0.f) * w2[4 * g + 0];
                acc1 += fmaxf(u[4 * g + 1] + v4.y, 0.f) * w2[4 * g + 1];
                acc2 += fmaxf(u[4 * g + 2] + v4.z, 0.f) * w2[4 * g + 2];
                acc3 += fmaxf(u[4 * g + 3] + v4.w, 0.f) * w2[4 * g + 3];
            }
        }
        part_s[jg][r] = (acc0 + acc1) + (acc2 + acc3);
        __syncthreads();
        if (t < 32) {
            float m = (float)NN * mb2[0];
#pragma unroll
            for (int g = 0; g < 8; ++g) m += part_s[g][t];
            msg_s[t] = m;
        }
        __syncthreads();

        // ---- stage 2: actor logits partial over this block's 32 rows ----
        // thread = (row r, k-group kg of 4 k's)
        {
            const int   kg    = t >> 5;       // 0..7
            const float msg_i = msg_s[r];
            float p[4];
#pragma unroll
            for (int kk = 0; kk < 4; ++kk) {
                const int k = kg * 4 + kk;
                p[kk] = msg_i * aw1[k] + coor_i * aw1[HH + k] + ab1[k];
            }
            float lacc[AA];
#pragma unroll
            for (int a = 0; a < AA; ++a) lacc[a] = 0.f;
#pragma unroll
            for (int a = 0; a < AA; ++a) {
                const float fa = (float)a;
#pragma unroll
                for (int kk = 0; kk < 4; ++kk) {
                    const int k = kg * 4 + kk;
                    lacc[a] += fmaxf(p[kk] + fa * aw1[2 * HH + k], 0.f) * aw2[k];
                }
            }
#pragma unroll
            for (int a = 0; a < AA; ++a) {
                float s = lacc[a];
#pragma unroll
                for (int off = 32; off > 0; off >>= 1) s += __shfl_xor(s, off);
                if (lane == 0) red_s[wave][a] = s;
            }
        }
        __syncthreads();
        if (t < AA)
            ws[(b * 4 + h) * 16 + t] =
                red_s[0][t] + red_s[1][t] + red_s[2][t] + red_s[3][t];
    } else {
        // ========================= critic block =========================
        const int b = blk - 4 * BB;
        if (t < NN) obs_s[t] = obs[b * NN + t];
        __syncthreads();

        {   // layer 1: 128 -> 256
            float a0 = 0.f, a1 = 0.f, a2 = 0.f, a3 = 0.f;
#pragma unroll 4
            for (int n = 0; n < NN; n += 4) {
                const float4 o4 = *(const float4*)&obs_s[n];
                a0 += o4.x * cw1[(n + 0) * MIDD + t];
                a1 += o4.y * cw1[(n + 1) * MIDD + t];
                a2 += o4.z * cw1[(n + 2) * MIDD + t];
                a3 += o4.w * cw1[(n + 3) * MIDD + t];
            }
            h1_s[t] = fmaxf(cb1[t] + ((a0 + a1) + (a2 + a3)), 0.f);
        }
        __syncthreads();
        {   // layer 2: 256 -> 256
            float a0 = 0.f, a1 = 0.f, a2 = 0.f, a3 = 0.f;
#pragma unroll 4
            for (int k = 0; k < MIDD; k += 4) {
                const float4 h4 = *(const float4*)&h1_s[k];
                a0 += h4.x * cw2[(k + 0) * MIDD + t];
                a1 += h4.y * cw2[(k + 1) * MIDD + t];
                a2 += h4.z * cw2[(k + 2) * MIDD + t];
                a3 += h4.w * cw2[(k + 3) * MIDD + t];
            }
            h2_s[t] = fmaxf(cb2[t] + ((a0 + a1) + (a2 + a3)), 0.f);
        }
        __syncthreads();
        {   // layer 3 + head
            float a0 = 0.f, a1 = 0.f, a2 = 0.f, a3 = 0.f;
#pragma unroll 4
            for (int k = 0; k < MIDD; k += 4) {
                const float4 h4 = *(const float4*)&h2_s[k];
                a0 += h4.x * cw3[(k + 0) * MIDD + t];
                a1 += h4.y * cw3[(k + 1) * MIDD + t];
                a2 += h4.z * cw3[(k + 2) * MIDD + t];
                a3 += h4.w * cw3[(k + 3) * MIDD + t];
            }
            const float h3 = fmaxf(cb3[t] + ((a0 + a1) + (a2 + a3)), 0.f);
            float pv = h3 * cw4[t];
#pragma unroll
            for (int off = 32; off > 0; off >>= 1) pv += __shfl_xor(pv, off);
            if (lane == 0) red_s[wave][0] = pv;
            __syncthreads();
            if (t == 0)
                out[BB * AA + b] =
                    red_s[0][0] + red_s[1][0] + red_s[2][0] + red_s[3][0] + cb4[0];
        }
    }
}

// ---------------- kernel 2: reduce the 4 logit partials ----------------
__global__ __launch_bounds__(64) void gacq_reduce(
    const float* __restrict__ ws, const float* __restrict__ ab2,
    float* __restrict__ out)
{
    const int idx = blockIdx.x * 64 + threadIdx.x;   // 0..3839 == b*15+a
    const int b   = idx / AA;
    const int a   = idx - b * AA;
    out[idx] = ws[(b * 4 + 0) * 16 + a] + ws[(b * 4 + 1) * 16 + a]
             + ws[(b * 4 + 2) * 16 + a] + ws[(b * 4 + 3) * 16 + a]
             + (float)NN * ab2[0];
}

extern "C" void kernel_launch(void* const* d_in, const int* in_sizes, int n_in,
                              void* d_out, int out_size, void* d_ws, size_t ws_size,
                              hipStream_t stream) {
    const float* obs = (const float*)d_in[0];
    const float* mw1 = (const float*)d_in[1];
    const float* mb1 = (const float*)d_in[2];
    const float* mw2 = (const float*)d_in[3];
    const float* mb2 = (const float*)d_in[4];
    const float* aw1 = (const float*)d_in[5];
    const float* ab1 = (const float*)d_in[6];
    const float* aw2 = (const float*)d_in[7];
    const float* ab2 = (const float*)d_in[8];
    const float* cw1 = (const float*)d_in[9];
    const float* cb1 = (const float*)d_in[10];
    const float* cw2 = (const float*)d_in[11];
    const float* cb2 = (const float*)d_in[12];
    const float* cw3 = (const float*)d_in[13];
    const float* cb3 = (const float*)d_in[14];
    const float* cw4 = (const float*)d_in[15];
    const float* cb4 = (const float*)d_in[16];
    float* out = (float*)d_out;
    float* ws  = (float*)d_ws;

    gacq_main<<<dim3(4 * BB + BB), dim3(256), 0, stream>>>(
        obs, mw1, mb1, mw2, mb2, aw1, ab1, aw2, ab2,
        cw1, cb1, cw2, cb2, cw3, cb3, cw4, cb4, out, ws);

    gacq_reduce<<<dim3(BB * AA / 64), dim3(64), 0, stream>>>(ws, ab2, out);
}

// Round 3
// 26.675 us; speedup vs baseline: 1.2258x; 1.0804x over previous
//
#include <hip/hip_runtime.h>

#define BB   256
#define NN   128
#define AA   15
#define HH   32
#define MIDD 256

__global__ __launch_bounds__(512, 4) void gacq_one(
    const float* __restrict__ obs,
    const float* __restrict__ mw1, const float* __restrict__ mb1,
    const float* __restrict__ mw2, const float* __restrict__ mb2,
    const float* __restrict__ aw1, const float* __restrict__ ab1,
    const float* __restrict__ aw2, const float* __restrict__ ab2,
    const float* __restrict__ cw1, const float* __restrict__ cb1,
    const float* __restrict__ cw2, const float* __restrict__ cb2,
    const float* __restrict__ cw3, const float* __restrict__ cb3,
    const float* __restrict__ cw4, const float* __restrict__ cb4,
    float* __restrict__ out)
{
    __shared__ __align__(16) float obs_s[2][NN];
    __shared__ __align__(16) float vp_s[NN][HH];          // v (stage1), then swizzled p (stage2)
    __shared__ __align__(16) float part_s[4][8][16][8];   // [jg][kg][rg][rr] 16 KB
    __shared__ float msg_s[NN];
    __shared__ __align__(16) float h_s[2][2][MIDD];       // critic activations
    __shared__ float redc_s[2][4];

    const int blk = blockIdx.x;
    const int t   = threadIdx.x;

    if (blk < BB) {
        // ===================== messenger + actor (one b per block) =====================
        const int b = blk;
        if (t < NN) obs_s[0][t] = obs[b * NN + t];
        __syncthreads();

        // v[j][k] = obs[j]*mw1[2][k] + coor_j*mw1[3][k] + mb1[k]
        for (int e = t; e < NN * HH; e += 512) {
            const int j = e >> 5, k = e & 31;
            vp_s[j][k] = obs_s[0][j] * mw1[2 * HH + k]
                       + ((float)j * (1.0f / (float)NN)) * mw1[3 * HH + k]
                       + mb1[k];
        }

        const int kg = t & 7;           // k = kg*4 + kk
        const int rg = (t >> 3) & 15;   // rows rg*8 + rr
        const int jg = t >> 7;          // j in [jg*32, jg*32+32)

        float u[8][4], w2[4];
#pragma unroll
        for (int kk = 0; kk < 4; ++kk) w2[kk] = mw2[kg * 4 + kk];
#pragma unroll
        for (int rr = 0; rr < 8; ++rr) {
            const int   row = rg * 8 + rr;
            const float ob  = obs_s[0][row];
            const float cr  = (float)row * (1.0f / (float)NN);
#pragma unroll
            for (int kk = 0; kk < 4; ++kk) {
                const int k = kg * 4 + kk;
                u[rr][kk] = ob * mw1[k] + cr * mw1[HH + k];
            }
        }
        __syncthreads();   // v ready

        // ---- stage 1: each thread: 8 rows x 4 k x 32 j; one b128 read per j ----
        float acc[8];
#pragma unroll
        for (int rr = 0; rr < 8; ++rr) acc[rr] = 0.f;
        const int j0 = jg * 32;
#pragma unroll 2
        for (int j = j0; j < j0 + 32; ++j) {
            const float4 v4 = *(const float4*)&vp_s[j][kg * 4];
#pragma unroll
            for (int rr = 0; rr < 8; ++rr) {
                acc[rr] += fmaxf(u[rr][0] + v4.x, 0.f) * w2[0];
                acc[rr] += fmaxf(u[rr][1] + v4.y, 0.f) * w2[1];
                acc[rr] += fmaxf(u[rr][2] + v4.z, 0.f) * w2[2];
                acc[rr] += fmaxf(u[rr][3] + v4.w, 0.f) * w2[3];
            }
        }
        *(float4*)&part_s[jg][kg][rg][0] = make_float4(acc[0], acc[1], acc[2], acc[3]);
        *(float4*)&part_s[jg][kg][rg][4] = make_float4(acc[4], acc[5], acc[6], acc[7]);
        __syncthreads();

        if (t < NN) {
            float m = (float)NN * mb2[0];
#pragma unroll
            for (int g = 0; g < 4; ++g)
#pragma unroll
                for (int q = 0; q < 8; ++q)
                    m += part_s[g][q][t >> 3][t & 7];
            msg_s[t] = m;
        }
        __syncthreads();

        // ---- stage p: p[row][k] = msg*aw1[0][k] + coor*aw1[1][k] + ab1[k],
        //      stored chunk-XOR-swizzled into vp_s: chunk c -> c ^ (row&7) ----
#pragma unroll
        for (int it = 0; it < 2; ++it) {
            const int   row = t & 127;
            const int   c   = (t >> 7) + it * 4;
            const float mi  = msg_s[row];
            const float cr  = (float)row * (1.0f / (float)NN);
            const int   k0  = c * 4;
            float4 p;
            p.x = mi * aw1[k0 + 0] + cr * aw1[HH + k0 + 0] + ab1[k0 + 0];
            p.y = mi * aw1[k0 + 1] + cr * aw1[HH + k0 + 1] + ab1[k0 + 1];
            p.z = mi * aw1[k0 + 2] + cr * aw1[HH + k0 + 2] + ab1[k0 + 2];
            p.w = mi * aw1[k0 + 3] + cr * aw1[HH + k0 + 3] + ab1[k0 + 3];
            *(float4*)&vp_s[row][(c ^ (row & 7)) * 4] = p;
        }
        __syncthreads();

        // ---- stage 2: a = t>>5 (16 groups, a=15 dummy), sub = t&31, rows sub+32m ----
        {
            const int   a   = t >> 5;
            const int   sub = t & 31;
            const float fa  = (float)a;
            float qa[HH];
#pragma unroll
            for (int k = 0; k < HH; ++k) qa[k] = fa * aw1[2 * HH + k];
            float s0 = 0.f, s1 = 0.f, s2 = 0.f, s3 = 0.f;
#pragma unroll
            for (int m = 0; m < 4; ++m) {
                const int row = sub + 32 * m;
                const int sw  = row & 7;
#pragma unroll
                for (int c = 0; c < 8; ++c) {
                    const float4 p4 = *(const float4*)&vp_s[row][(c ^ sw) * 4];
                    const int    k0 = c * 4;
                    s0 += fmaxf(p4.x + qa[k0 + 0], 0.f) * aw2[k0 + 0];
                    s1 += fmaxf(p4.y + qa[k0 + 1], 0.f) * aw2[k0 + 1];
                    s2 += fmaxf(p4.z + qa[k0 + 2], 0.f) * aw2[k0 + 2];
                    s3 += fmaxf(p4.w + qa[k0 + 3], 0.f) * aw2[k0 + 3];
                }
            }
            float s = (s0 + s1) + (s2 + s3);
#pragma unroll
            for (int off = 1; off < 32; off <<= 1) s += __shfl_xor(s, off);
            if (sub == 0 && a < AA)
                out[b * AA + a] = s + (float)NN * ab2[0];
        }
    } else {
        // ========================= critic: 2 batch elems per block =========================
        const int half = t >> 8;         // 0/1
        const int tt   = t & 255;
        const int b    = (blk - BB) * 2 + half;
        const int lane = t & 63;

        if (tt < NN) obs_s[half][tt] = obs[b * NN + tt];
        __syncthreads();

        {   // layer 1: 128 -> 256
            float a0 = 0.f, a1 = 0.f, a2 = 0.f, a3 = 0.f;
#pragma unroll 4
            for (int n = 0; n < NN; n += 4) {
                const float4 o4 = *(const float4*)&obs_s[half][n];
                a0 += o4.x * cw1[(n + 0) * MIDD + tt];
                a1 += o4.y * cw1[(n + 1) * MIDD + tt];
                a2 += o4.z * cw1[(n + 2) * MIDD + tt];
                a3 += o4.w * cw1[(n + 3) * MIDD + tt];
            }
            h_s[half][0][tt] = fmaxf(cb1[tt] + ((a0 + a1) + (a2 + a3)), 0.f);
        }
        __syncthreads();
        {   // layer 2: 256 -> 256
            float a0 = 0.f, a1 = 0.f, a2 = 0.f, a3 = 0.f;
#pragma unroll 4
            for (int k = 0; k < MIDD; k += 4) {
                const float4 h4 = *(const float4*)&h_s[half][0][k];
                a0 += h4.x * cw2[(k + 0) * MIDD + tt];
                a1 += h4.y * cw2[(k + 1) * MIDD + tt];
                a2 += h4.z * cw2[(k + 2) * MIDD + tt];
                a3 += h4.w * cw2[(k + 3) * MIDD + tt];
            }
            h_s[half][1][tt] = fmaxf(cb2[tt] + ((a0 + a1) + (a2 + a3)), 0.f);
        }
        __syncthreads();
        {   // layer 3 + head
            float a0 = 0.f, a1 = 0.f, a2 = 0.f, a3 = 0.f;
#pragma unroll 4
            for (int k = 0; k < MIDD; k += 4) {
                const float4 h4 = *(const float4*)&h_s[half][1][k];
                a0 += h4.x * cw3[(k + 0) * MIDD + tt];
                a1 += h4.y * cw3[(k + 1) * MIDD + tt];
                a2 += h4.z * cw3[(k + 2) * MIDD + tt];
                a3 += h4.w * cw3[(k + 3) * MIDD + tt];
            }
            const float h3 = fmaxf(cb3[tt] + ((a0 + a1) + (a2 + a3)), 0.f);
            float pv = h3 * cw4[tt];
#pragma unroll
            for (int off = 32; off > 0; off >>= 1) pv += __shfl_xor(pv, off);
            if (lane == 0) redc_s[half][(t >> 6) & 3] = pv;
            __syncthreads();
            if (tt == 0)
                out[BB * AA + b] = redc_s[half][0] + redc_s[half][1]
                                 + redc_s[half][2] + redc_s[half][3] + cb4[0];
        }
    }
}

extern "C" void kernel_launch(void* const* d_in, const int* in_sizes, int n_in,
                              void* d_out, int out_size, void* d_ws, size_t ws_size,
                              hipStream_t stream) {
    const float* obs = (const float*)d_in[0];
    const float* mw1 = (const float*)d_in[1];
    const float* mb1 = (const float*)d_in[2];
    const float* mw2 = (const float*)d_in[3];
    const float* mb2 = (const float*)d_in[4];
    const float* aw1 = (const float*)d_in[5];
    const float* ab1 = (const float*)d_in[6];
    const float* aw2 = (const float*)d_in[7];
    const float* ab2 = (const float*)d_in[8];
    const float* cw1 = (const float*)d_in[9];
    const float* cb1 = (const float*)d_in[10];
    const float* cw2 = (const float*)d_in[11];
    const float* cb2 = (const float*)d_in[12];
    const float* cw3 = (const float*)d_in[13];
    const float* cb3 = (const float*)d_in[14];
    const float* cw4 = (const float*)d_in[15];
    const float* cb4 = (const float*)d_in[16];
    float* out = (float*)d_out;

    gacq_one<<<dim3(BB + BB / 2), dim3(512), 0, stream>>>(
        obs, mw1, mb1, mw2, mb2, aw1, ab1, aw2, ab2,
        cw1, cb1, cw2, cb2, cw3, cb3, cw4, cb4, out);
}

// Round 4
// 19.694 us; speedup vs baseline: 1.6603x; 1.3545x over previous
//
#include <hip/hip_runtime.h>

#define BB   256
#define NN   128
#define AA   15
#define HH   32
#define MIDD 256

// aux_s layout: [0:128) mw1 | [128:224) aw1(rows0-2) | [224:256) ab1
//               [256:288) aw2 | [288:320) mw2 | [320:352) mb1 | [352] mb2 | [353] ab2
__global__ __launch_bounds__(512, 4) void gacq_v4(
    const float* __restrict__ obs,
    const float* __restrict__ mw1, const float* __restrict__ mb1,
    const float* __restrict__ mw2, const float* __restrict__ mb2,
    const float* __restrict__ aw1, const float* __restrict__ ab1,
    const float* __restrict__ aw2, const float* __restrict__ ab2,
    const float* __restrict__ cw1, const float* __restrict__ cb1,
    const float* __restrict__ cw2, const float* __restrict__ cb2,
    const float* __restrict__ cw3, const float* __restrict__ cb3,
    const float* __restrict__ cw4, const float* __restrict__ cb4,
    float* __restrict__ out)
{
    __shared__ __align__(16) float aux_s[356];
    __shared__ __align__(16) float obs_s[NN];
    __shared__ __align__(16) float vp_s[NN][HH];          // v (stage1) then swizzled p (stage2)
    __shared__ __align__(16) float part_s[4][8][16][8];   // [jg][kg][rg][rr]
    __shared__ __align__(16) float msg_s[NN];
    __shared__ __align__(16) float cpart_s[8][MIDD];      // critic k-split partials
    __shared__ __align__(16) float h_s[2][MIDD];
    __shared__ float red_s[4];

    const int blk = blockIdx.x;
    const int t   = threadIdx.x;

    if (blk < BB) {
        // ===================== messenger + actor (one b per block) =====================
        const int b = blk;

        // stage small weights into LDS (issued before first barrier; latency hidden)
        if (t < 354) {
            float v;
            if      (t < 128) v = mw1[t];
            else if (t < 224) v = aw1[t - 128];
            else if (t < 256) v = ab1[t - 224];
            else if (t < 288) v = aw2[t - 256];
            else if (t < 320) v = mw2[t - 288];
            else if (t < 352) v = mb1[t - 320];
            else if (t == 352) v = mb2[0];
            else               v = ab2[0];
            aux_s[t] = v;
        }
        if (t < NN) obs_s[t] = obs[b * NN + t];
        __syncthreads();

        // v[j][k] = obs[j]*mw1[2][k] + coor_j*mw1[3][k] + mb1[k]
        for (int e = t; e < NN * HH; e += 512) {
            const int j = e >> 5, k = e & 31;
            vp_s[j][k] = obs_s[j] * aux_s[64 + k]
                       + ((float)j * (1.0f / (float)NN)) * aux_s[96 + k]
                       + aux_s[320 + k];
        }

        const int kg = t & 7;           // k = kg*4 + kk
        const int rg = (t >> 3) & 15;   // rows rg*8 + rr
        const int jg = t >> 7;          // j in [jg*32, jg*32+32)

        float u[8][4];
        const float w20 = aux_s[288 + kg * 4 + 0];
        const float w21 = aux_s[288 + kg * 4 + 1];
        const float w22 = aux_s[288 + kg * 4 + 2];
        const float w23 = aux_s[288 + kg * 4 + 3];
#pragma unroll
        for (int rr = 0; rr < 8; ++rr) {
            const int   row = rg * 8 + rr;
            const float ob  = obs_s[row];
            const float cr  = (float)row * (1.0f / (float)NN);
#pragma unroll
            for (int kk = 0; kk < 4; ++kk)
                u[rr][kk] = ob * aux_s[kg * 4 + kk] + cr * aux_s[32 + kg * 4 + kk];
        }
        __syncthreads();   // v ready

        // ---- stage 1: 8 rows x 4 k x 32 j, software-pipelined LDS read ----
        float acc[8];
#pragma unroll
        for (int rr = 0; rr < 8; ++rr) acc[rr] = 0.f;
        const int    j0    = jg * 32;
        const float* vbase = &vp_s[0][kg * 4];
        float4 vc = *(const float4*)(vbase + j0 * HH);
#pragma unroll 4
        for (int jj = 0; jj < 32; ++jj) {
            const int    nj = j0 + ((jj + 1) & 31);
            const float4 vn = *(const float4*)(vbase + nj * HH);
#pragma unroll
            for (int rr = 0; rr < 8; ++rr) {
                acc[rr] += fmaxf(u[rr][0] + vc.x, 0.f) * w20;
                acc[rr] += fmaxf(u[rr][1] + vc.y, 0.f) * w21;
                acc[rr] += fmaxf(u[rr][2] + vc.z, 0.f) * w22;
                acc[rr] += fmaxf(u[rr][3] + vc.w, 0.f) * w23;
            }
            vc = vn;
        }
        *(float4*)&part_s[jg][kg][rg][0] = make_float4(acc[0], acc[1], acc[2], acc[3]);
        *(float4*)&part_s[jg][kg][rg][4] = make_float4(acc[4], acc[5], acc[6], acc[7]);
        __syncthreads();

        if (t < NN) {
            float m = (float)NN * aux_s[352];
#pragma unroll
            for (int g = 0; g < 4; ++g)
#pragma unroll
                for (int q = 0; q < 8; ++q)
                    m += part_s[g][q][t >> 3][t & 7];
            msg_s[t] = m;
        }
        __syncthreads();

        // ---- stage p: p[row][k] chunk-XOR-swizzled into vp_s ----
#pragma unroll
        for (int it = 0; it < 2; ++it) {
            const int   row = t & 127;
            const int   c   = (t >> 7) + it * 4;
            const float mi  = msg_s[row];
            const float cr  = (float)row * (1.0f / (float)NN);
            const int   k0  = c * 4;
            float4 p;
            p.x = mi * aux_s[128 + k0 + 0] + cr * aux_s[160 + k0 + 0] + aux_s[224 + k0 + 0];
            p.y = mi * aux_s[128 + k0 + 1] + cr * aux_s[160 + k0 + 1] + aux_s[224 + k0 + 1];
            p.z = mi * aux_s[128 + k0 + 2] + cr * aux_s[160 + k0 + 2] + aux_s[224 + k0 + 2];
            p.w = mi * aux_s[128 + k0 + 3] + cr * aux_s[160 + k0 + 3] + aux_s[224 + k0 + 3];
            *(float4*)&vp_s[row][(c ^ (row & 7)) * 4] = p;
        }
        __syncthreads();

        // ---- stage 2: a = t>>5 (16 groups, a=15 dummy), sub = t&31, rows sub+32m ----
        {
            const int   a   = t >> 5;
            const int   sub = t & 31;
            const float fa  = (float)a;
            float qa[HH];
#pragma unroll
            for (int k = 0; k < HH; ++k) qa[k] = fa * aux_s[192 + k];
            float s0 = 0.f, s1 = 0.f, s2 = 0.f, s3 = 0.f;
#pragma unroll
            for (int m = 0; m < 4; ++m) {
                const int row = sub + 32 * m;
                const int sw  = row & 7;
#pragma unroll
                for (int c = 0; c < 8; ++c) {
                    const float4 p4 = *(const float4*)&vp_s[row][(c ^ sw) * 4];
                    const float4 w4 = *(const float4*)&aux_s[256 + c * 4];
                    const int    k0 = c * 4;
                    s0 += fmaxf(p4.x + qa[k0 + 0], 0.f) * w4.x;
                    s1 += fmaxf(p4.y + qa[k0 + 1], 0.f) * w4.y;
                    s2 += fmaxf(p4.z + qa[k0 + 2], 0.f) * w4.z;
                    s3 += fmaxf(p4.w + qa[k0 + 3], 0.f) * w4.w;
                }
            }
            float s = (s0 + s1) + (s2 + s3);
#pragma unroll
            for (int off = 1; off < 32; off <<= 1) s += __shfl_xor(s, off);
            if (sub == 0 && a < AA)
                out[b * AA + a] = s + (float)NN * aux_s[353];
        }
    } else {
        // ===================== critic (one b per block, k-split) =====================
        const int b = blk - BB;
        if (t < NN) obs_s[t] = obs[b * NN + t];
        __syncthreads();

        const int q = t & 63;     // output quad: units 4q..4q+3
        const int s = t >> 6;     // k-slice

        {   // layer 1: 128 -> 256, k-slice of 16
            float4 acc = make_float4(0.f, 0.f, 0.f, 0.f);
            const int k0 = s * 16;
#pragma unroll 4
            for (int k = k0; k < k0 + 16; ++k) {
                const float4 w = *(const float4*)&cw1[k * MIDD + q * 4];
                const float  h = obs_s[k];
                acc.x += h * w.x; acc.y += h * w.y; acc.z += h * w.z; acc.w += h * w.w;
            }
            *(float4*)&cpart_s[s][q * 4] = acc;
        }
        __syncthreads();
        if (t < MIDD) {
            float sum = cb1[t];
#pragma unroll
            for (int s8 = 0; s8 < 8; ++s8) sum += cpart_s[s8][t];
            h_s[0][t] = fmaxf(sum, 0.f);
        }
        __syncthreads();

        {   // layer 2: 256 -> 256, k-slice of 32
            float4 acc = make_float4(0.f, 0.f, 0.f, 0.f);
            const int k0 = s * 32;
#pragma unroll 4
            for (int k = k0; k < k0 + 32; ++k) {
                const float4 w = *(const float4*)&cw2[k * MIDD + q * 4];
                const float  h = h_s[0][k];
                acc.x += h * w.x; acc.y += h * w.y; acc.z += h * w.z; acc.w += h * w.w;
            }
            *(float4*)&cpart_s[s][q * 4] = acc;
        }
        __syncthreads();
        if (t < MIDD) {
            float sum = cb2[t];
#pragma unroll
            for (int s8 = 0; s8 < 8; ++s8) sum += cpart_s[s8][t];
            h_s[1][t] = fmaxf(sum, 0.f);
        }
        __syncthreads();

        {   // layer 3: 256 -> 256, k-slice of 32
            float4 acc = make_float4(0.f, 0.f, 0.f, 0.f);
            const int k0 = s * 32;
#pragma unroll 4
            for (int k = k0; k < k0 + 32; ++k) {
                const float4 w = *(const float4*)&cw3[k * MIDD + q * 4];
                const float  h = h_s[1][k];
                acc.x += h * w.x; acc.y += h * w.y; acc.z += h * w.z; acc.w += h * w.w;
            }
            *(float4*)&cpart_s[s][q * 4] = acc;
        }
        __syncthreads();
        if (t < MIDD) {   // layer-3 finish + head
            float sum = cb3[t];
#pragma unroll
            for (int s8 = 0; s8 < 8; ++s8) sum += cpart_s[s8][t];
            const float h3 = fmaxf(sum, 0.f);
            float pv = h3 * cw4[t];
#pragma unroll
            for (int off = 32; off > 0; off >>= 1) pv += __shfl_xor(pv, off);
            if ((t & 63) == 0) red_s[t >> 6] = pv;
        }
        __syncthreads();
        if (t == 0)
            out[BB * AA + b] = red_s[0] + red_s[1] + red_s[2] + red_s[3] + cb4[0];
    }
}

extern "C" void kernel_launch(void* const* d_in, const int* in_sizes, int n_in,
                              void* d_out, int out_size, void* d_ws, size_t ws_size,
                              hipStream_t stream) {
    const float* obs = (const float*)d_in[0];
    const float* mw1 = (const float*)d_in[1];
    const float* mb1 = (const float*)d_in[2];
    const float* mw2 = (const float*)d_in[3];
    const float* mb2 = (const float*)d_in[4];
    const float* aw1 = (const float*)d_in[5];
    const float* ab1 = (const float*)d_in[6];
    const float* aw2 = (const float*)d_in[7];
    const float* ab2 = (const float*)d_in[8];
    const float* cw1 = (const float*)d_in[9];
    const float* cb1 = (const float*)d_in[10];
    const float* cw2 = (const float*)d_in[11];
    const float* cb2 = (const float*)d_in[12];
    const float* cw3 = (const float*)d_in[13];
    const float* cb3 = (const float*)d_in[14];
    const float* cw4 = (const float*)d_in[15];
    const float* cb4 = (const float*)d_in[16];
    float* out = (float*)d_out;

    gacq_v4<<<dim3(2 * BB), dim3(512), 0, stream>>>(
        obs, mw1, mb1, mw2, mb2, aw1, ab1, aw2, ab2,
        cw1, cb1, cw2, cb2, cw3, cb3, cw4, cb4, out);
}